// Round 3
// baseline (531.766 us; speedup 1.0000x reference)
//
#include <hip/hip_runtime.h>
#include <hip/hip_fp16.h>

typedef _Float16 half8 __attribute__((ext_vector_type(8)));
typedef _Float16 half4v __attribute__((ext_vector_type(4)));
typedef float floatx4 __attribute__((ext_vector_type(4)));

// ---------------- async global->LDS (16B per lane) ----------------
__device__ __forceinline__ void load_lds16(const void* g, void* l) {
    __builtin_amdgcn_global_load_lds(
        (const __attribute__((address_space(1))) void*)g,
        (__attribute__((address_space(3))) void*)l,
        16, 0, 0);
}

// Stage one 128x64 fp16 half-tile (16 KiB) into LDS. LDS dest is linear
// (global_load_lds requirement); the SOURCE slot is XOR-pre-swizzled
// (slot ^= row&7) so a swizzled reader sees natural data (Guideline 21).
__device__ __forceinline__ void stage_half(const _Float16* g, long ld, _Float16* dst) {
    const int t = threadIdx.x;  // 512 threads x 2 chunks x 16B
#pragma unroll
    for (int j = 0; j < 2; ++j) {
        const int c = j * 512 + t;             // 0..1023
        const int row = c >> 3;                // 0..127
        const int slot = (c & 7) ^ (row & 7);  // pre-swizzled source slot
        load_lds16(g + (long)row * ld + slot * 8, dst + c * 8);
    }
}

// ---------------- 256x256 8-phase gemm_bt core ----------------
// C[m,n] += sum_k A[m,k]*B[n,k]. BM=BN=256, BK=64, 512 threads = 8 waves
// (2M x 4N); per-wave 128x64 output = 8x4 frags of 16x16, mfma 16x16x32 f16.
// LDS: 2 tile-buffers x (A + B) x 2 halves x 16KB = 128 KiB (dynamic).
// 8 phases / 2 K-tiles; counted vmcnt(4) at phases 4 and 8 only.
// Stage slot schedule (race-checked): A-halves last read P1/P5, B-halves
// last read P4/P8; every stage targets a slot free for >=1 barrier.
__device__ __forceinline__ void gemm256_core(const _Float16* A, long lda,
                                             const _Float16* B, long ldb,
                                             int K, floatx4 acc[8][4],
                                             _Float16* lds) {
    const int lane = threadIdx.x & 63;
    const int w    = threadIdx.x >> 6;   // 0..7
    const int wr   = w >> 2;             // 0..1
    const int wc   = w & 3;              // 0..3
    const int rsel = lane & 15, gsel = lane >> 4;
    const int NT = K >> 6, NI = NT >> 1;

#define ASLOT(BUF, H) (lds + (BUF) * 32768 + (H) * 8192)
#define BSLOT(BUF, H) (lds + (BUF) * 32768 + 16384 + (H) * 8192)
#define STAGE_A(BUF, H, KT) stage_half(A + (long)(H) * 128 * lda + (KT) * 64, lda, ASLOT(BUF, H))
#define STAGE_B(BUF, H, KT) stage_half(B + (long)(H) * 128 * ldb + (KT) * 64, ldb, BSLOT(BUF, H))
#define LOAD_AF(BUF)                                                               \
    {                                                                              \
        const _Float16* Ah = ASLOT(BUF, wr);                                       \
        _Pragma("unroll") for (int m = 0; m < 8; ++m) {                            \
            const int r = m * 16 + rsel;                                           \
            af[m][0] = *(const half8*)&Ah[r * 64 + ((gsel ^ (r & 7)) << 3)];       \
            af[m][1] = *(const half8*)&Ah[r * 64 + (((4 + gsel) ^ (r & 7)) << 3)]; \
        }                                                                          \
    }
#define LOAD_BF(BUF, NF)                                                           \
    {                                                                              \
        const _Float16* Bh = BSLOT(BUF, wc >> 1);                                  \
        const int rn = (wc & 1) * 64 + (NF) * 16 + rsel;                           \
        b0 = *(const half8*)&Bh[rn * 64 + ((gsel ^ (rn & 7)) << 3)];               \
        b1 = *(const half8*)&Bh[rn * 64 + (((4 + gsel) ^ (rn & 7)) << 3)];         \
    }
#define SYNC_COMPUTE(NF)                                                           \
    __builtin_amdgcn_sched_barrier(0);                                             \
    __builtin_amdgcn_s_barrier();                                                  \
    asm volatile("s_waitcnt lgkmcnt(0)" ::: "memory");                             \
    __builtin_amdgcn_sched_barrier(0);                                             \
    __builtin_amdgcn_s_setprio(1);                                                 \
    _Pragma("unroll") for (int m = 0; m < 8; ++m) {                                \
        acc[m][NF] = __builtin_amdgcn_mfma_f32_16x16x32_f16(af[m][0], b0, acc[m][NF], 0, 0, 0); \
        acc[m][NF] = __builtin_amdgcn_mfma_f32_16x16x32_f16(af[m][1], b1, acc[m][NF], 0, 0, 0); \
    }                                                                              \
    __builtin_amdgcn_s_setprio(0);                                                 \
    __builtin_amdgcn_s_barrier();                                                  \
    __builtin_amdgcn_sched_barrier(0);

    half8 af[8][2], b0, b1;

    // prologue: tile0 fully staged, tile1 A-halves in flight (4 loads)
    STAGE_A(0, 0, 0); STAGE_A(0, 1, 0); STAGE_B(0, 0, 0); STAGE_B(0, 1, 0);
    STAGE_A(1, 0, 1); STAGE_A(1, 1, 1);
    asm volatile("s_waitcnt vmcnt(4)" ::: "memory");
    __builtin_amdgcn_s_barrier();
    __builtin_amdgcn_sched_barrier(0);

#pragma unroll 1
    for (int i = 0; i < NI; ++i) {
        const int t1 = 2 * i + 1;
        const int s2 = (2 * i + 2 < NT) ? 2 * i + 2 : NT - 1;  // tail clamp:
        const int s3 = (2 * i + 3 < NT) ? 2 * i + 3 : NT - 1;  // never consumed
        // P1..P4: compute tile 2i (buf0), n-frag per phase
        LOAD_AF(0); LOAD_BF(0, 0); STAGE_B(1, 0, t1); SYNC_COMPUTE(0);
        LOAD_BF(0, 1); STAGE_B(1, 1, t1); SYNC_COMPUTE(1);
        LOAD_BF(0, 2); STAGE_A(0, 0, s2); SYNC_COMPUTE(2);
        LOAD_BF(0, 3); STAGE_A(0, 1, s2);
        asm volatile("s_waitcnt vmcnt(4)" ::: "memory");  // tile 2i+1 landed
        SYNC_COMPUTE(3);
        // P5..P8: compute tile 2i+1 (buf1)
        LOAD_AF(1); LOAD_BF(1, 0); STAGE_B(0, 0, s2); SYNC_COMPUTE(0);
        LOAD_BF(1, 1); STAGE_B(0, 1, s2); SYNC_COMPUTE(1);
        LOAD_BF(1, 2); STAGE_A(1, 0, s3); SYNC_COMPUTE(2);
        LOAD_BF(1, 3); STAGE_A(1, 1, s3);
        asm volatile("s_waitcnt vmcnt(4)" ::: "memory");  // tile 2i+2 landed
        SYNC_COMPUTE(3);
    }
    asm volatile("s_waitcnt vmcnt(0)" ::: "memory");
#undef ASLOT
#undef BSLOT
#undef STAGE_A
#undef STAGE_B
#undef LOAD_AF
#undef LOAD_BF
#undef SYNC_COMPUTE
}

__device__ __forceinline__ void zero_acc8(floatx4 acc[8][4]) {
    const floatx4 z = {0.f, 0.f, 0.f, 0.f};
#pragma unroll
    for (int m = 0; m < 8; ++m)
#pragma unroll
        for (int n = 0; n < 4; ++n) acc[m][n] = z;
}

// ---------------- kernels ----------------

// concat embeddings [B,S,256|256|512] fp32 -> X fp16 [16384][1024]
__global__ __launch_bounds__(256) void build_x_kernel(const float* e1, const float* e2,
                                                      const float* e3, _Float16* X) {
    long i = ((long)blockIdx.x * 256 + threadIdx.x) * 4;
    int m = (int)(i >> 10);
    int c = (int)(i & 1023);
    const float* src;
    if (c < 256)      src = e1 + (long)m * 256 + c;
    else if (c < 512) src = e2 + (long)m * 256 + (c - 256);
    else              src = e3 + (long)m * 512 + (c - 512);
    float4 f = *(const float4*)src;
    half4v h;
    h[0] = (_Float16)f.x; h[1] = (_Float16)f.y;
    h[2] = (_Float16)f.z; h[3] = (_Float16)f.w;
    *(half4v*)&X[i] = h;
}

// Wq,Wk,Wv,Wf fp32 [1024][1024] -> Wh fp16 [4][1024][1024]
__global__ __launch_bounds__(256) void conv_w_kernel(const float* Wq, const float* Wk,
                                                     const float* Wv, const float* Wf,
                                                     _Float16* dst) {
    long i = ((long)blockIdx.x * 256 + threadIdx.x) * 4;
    int which = (int)(i >> 20);
    long off = i & 1048575;
    const float* w = which == 0 ? Wq : which == 1 ? Wk : which == 2 ? Wv : Wf;
    float4 f = *(const float4*)(w + off);
    half4v h;
    h[0] = (_Float16)f.x; h[1] = (_Float16)f.y;
    h[2] = (_Float16)f.z; h[3] = (_Float16)f.w;
    *(half4v*)&dst[i] = h;
}

// QKV projection: z=0 -> q, z=1 -> k (row-major [16384][1024]),
// z=2 -> v written TRANSPOSED as vT [1024][16384].
__global__ __launch_bounds__(512, 2) void qkv_kernel(const _Float16* X, const _Float16* W,
                                                     const float* bq, const float* bk,
                                                     const float* bv, _Float16* q,
                                                     _Float16* k, _Float16* vT) {
    extern __shared__ _Float16 lds[];
    const int m0 = blockIdx.x * 256;
    const int n0 = blockIdx.y * 256;
    const int z  = blockIdx.z;
    floatx4 acc[8][4];
    zero_acc8(acc);
    gemm256_core(X + (long)m0 * 1024, 1024,
                 W + (long)z * 1048576 + (long)n0 * 1024, 1024, 1024, acc, lds);

    const float* bias = (z == 0) ? bq : (z == 1) ? bk : bv;
    const int lane = threadIdx.x & 63;
    const int w = threadIdx.x >> 6;
    const int wr = w >> 2, wc = w & 3;
    const int r0 = m0 + wr * 128 + (lane >> 4) * 4;
    const int c0 = n0 + wc * 64 + (lane & 15);
#pragma unroll
    for (int m = 0; m < 8; ++m) {
#pragma unroll
        for (int n = 0; n < 4; ++n) {
            const int r = r0 + m * 16;
            const int c = c0 + n * 16;
            const float bb = bias[c];
            if (z == 2) {
                half4v vv;
#pragma unroll
                for (int j = 0; j < 4; ++j) vv[j] = (_Float16)(acc[m][n][j] + bb);
                *(half4v*)&vT[(long)c * 16384 + r] = vv;
            } else {
                _Float16* dst = (z == 0) ? q : k;
#pragma unroll
                for (int j = 0; j < 4; ++j)
                    dst[(long)(r + j) * 1024 + c] = (_Float16)(acc[m][n][j] + bb);
            }
        }
    }
}

// scores[b] = q[b] @ k[b]^T  (fp32 out, chunk-local batch index bz)
__global__ __launch_bounds__(512, 2) void scores_kernel(const _Float16* qh,
                                                        const _Float16* kh, float* scores,
                                                        int b0) {
    extern __shared__ _Float16 lds[];
    const int m0 = blockIdx.x * 256;
    const int n0 = blockIdx.y * 256;
    const int bz = blockIdx.z;
    const int batch = b0 + bz;
    float* C = scores + (long)bz * 2048 * 2048;
    floatx4 acc[8][4];
    zero_acc8(acc);
    gemm256_core(qh + ((long)batch * 2048 + m0) * 1024, 1024,
                 kh + ((long)batch * 2048 + n0) * 1024, 1024, 1024, acc, lds);

    const int lane = threadIdx.x & 63;
    const int w = threadIdx.x >> 6;
    const int wr = w >> 2, wc = w & 3;
    const int r0 = m0 + wr * 128 + (lane >> 4) * 4;
    const int c0 = n0 + wc * 64 + (lane & 15);
#pragma unroll
    for (int m = 0; m < 8; ++m) {
#pragma unroll
        for (int n = 0; n < 4; ++n) {
            const int r = r0 + m * 16;
            const int c = c0 + n * 16;
#pragma unroll
            for (int j = 0; j < 4; ++j)
                C[(long)(r + j) * 2048 + c] = acc[m][n][j];
        }
    }
}

// row softmax over 2048 fp32 scores -> fp16 probs. one block per row.
__global__ __launch_bounds__(256) void softmax_kernel(const float* scores,
                                                      _Float16* probs, int b0) {
    const int row = blockIdx.x;
    const int bz  = blockIdx.y;
    const float* s = scores + ((long)bz * 2048 + row) * 2048;
    _Float16* p = probs + ((long)(b0 + bz) * 2048 + row) * 2048;
    const int t = threadIdx.x;

    float4 x0 = ((const float4*)s)[t * 2];
    float4 x1 = ((const float4*)s)[t * 2 + 1];
    float v[8] = {x0.x, x0.y, x0.z, x0.w, x1.x, x1.y, x1.z, x1.w};

    float mx = v[0];
#pragma unroll
    for (int j = 1; j < 8; ++j) mx = fmaxf(mx, v[j]);
#pragma unroll
    for (int d = 1; d < 64; d <<= 1) mx = fmaxf(mx, __shfl_xor(mx, d));
    __shared__ float smax[4];
    __shared__ float ssum[4];
    if ((t & 63) == 0) smax[t >> 6] = mx;
    __syncthreads();
    mx = fmaxf(fmaxf(smax[0], smax[1]), fmaxf(smax[2], smax[3]));

    float e[8];
    float sum = 0.f;
#pragma unroll
    for (int j = 0; j < 8; ++j) {
        e[j] = __expf(v[j] - mx);
        sum += e[j];
    }
#pragma unroll
    for (int d = 1; d < 64; d <<= 1) sum += __shfl_xor(sum, d);
    if ((t & 63) == 0) ssum[t >> 6] = sum;
    __syncthreads();
    sum = ssum[0] + ssum[1] + ssum[2] + ssum[3];
    const float inv = 1.0f / sum;

    half8 o;
#pragma unroll
    for (int j = 0; j < 8; ++j) o[j] = (_Float16)(e[j] * inv);
    *(half8*)&p[t * 8] = o;
}

// weighted[b] = probs[b] @ v[b] via vT (gemm_bt form). fp16 out [16384][1024].
__global__ __launch_bounds__(512, 2) void pv_kernel(const _Float16* probs,
                                                    const _Float16* vT, _Float16* wt) {
    extern __shared__ _Float16 lds[];
    const int m0 = blockIdx.x * 256;
    const int n0 = blockIdx.y * 256;
    const int batch = blockIdx.z;
    floatx4 acc[8][4];
    zero_acc8(acc);
    gemm256_core(probs + ((long)batch * 2048 + m0) * 2048, 2048,
                 vT + (long)n0 * 16384 + (long)batch * 2048, 16384, 2048, acc, lds);

    const int lane = threadIdx.x & 63;
    const int w = threadIdx.x >> 6;
    const int wr = w >> 2, wc = w & 3;
    const int r0 = wr * 128 + (lane >> 4) * 4;
    const int c0 = n0 + wc * 64 + (lane & 15);
#pragma unroll
    for (int m = 0; m < 8; ++m) {
#pragma unroll
        for (int n = 0; n < 4; ++n) {
            const int r = r0 + m * 16;
            const int c = c0 + n * 16;
#pragma unroll
            for (int j = 0; j < 4; ++j)
                wt[((long)batch * 2048 + m0 + r + j) * 1024 + c] =
                    (_Float16)acc[m][n][j];
        }
    }
}

// out = leakyrelu(weighted @ Wf^T + bf), fp32 out.
__global__ __launch_bounds__(512, 2) void out_kernel(const _Float16* wt, const _Float16* Wf,
                                                     const float* bf_, float* out) {
    extern __shared__ _Float16 lds[];
    const int m0 = blockIdx.x * 256;
    const int n0 = blockIdx.y * 256;
    floatx4 acc[8][4];
    zero_acc8(acc);
    gemm256_core(wt + (long)m0 * 1024, 1024, Wf + (long)n0 * 1024, 1024, 1024, acc, lds);

    const int lane = threadIdx.x & 63;
    const int w = threadIdx.x >> 6;
    const int wr = w >> 2, wc = w & 3;
    const int r0 = m0 + wr * 128 + (lane >> 4) * 4;
    const int c0 = n0 + wc * 64 + (lane & 15);
#pragma unroll
    for (int m = 0; m < 8; ++m) {
#pragma unroll
        for (int n = 0; n < 4; ++n) {
            const int r = r0 + m * 16;
            const int c = c0 + n * 16;
            const float bb = bf_[c];
#pragma unroll
            for (int j = 0; j < 4; ++j) {
                float y = acc[m][n][j] + bb;
                y = (y >= 0.f) ? y : 0.2f * y;
                out[(long)(r + j) * 1024 + c] = y;
            }
        }
    }
}

// ---------------- launcher ----------------
extern "C" void kernel_launch(void* const* d_in, const int* in_sizes, int n_in,
                              void* d_out, int out_size, void* d_ws, size_t ws_size,
                              hipStream_t stream) {
    const float* e1 = (const float*)d_in[0];
    const float* e2 = (const float*)d_in[1];
    const float* e3 = (const float*)d_in[2];
    const float* Wq = (const float*)d_in[3];
    const float* bq = (const float*)d_in[4];
    const float* Wk = (const float*)d_in[5];
    const float* bk = (const float*)d_in[6];
    const float* Wv = (const float*)d_in[7];
    const float* bv = (const float*)d_in[8];
    const float* Wf = (const float*)d_in[9];
    const float* bf_ = (const float*)d_in[10];
    float* out = (float*)d_out;

    // raise dynamic-LDS cap to 128 KiB (idempotent; not a stream op)
    const int LDS_BYTES = 131072;
    (void)hipFuncSetAttribute((const void*)qkv_kernel,
                              hipFuncAttributeMaxDynamicSharedMemorySize, LDS_BYTES);
    (void)hipFuncSetAttribute((const void*)scores_kernel,
                              hipFuncAttributeMaxDynamicSharedMemorySize, LDS_BYTES);
    (void)hipFuncSetAttribute((const void*)pv_kernel,
                              hipFuncAttributeMaxDynamicSharedMemorySize, LDS_BYTES);
    (void)hipFuncSetAttribute((const void*)out_kernel,
                              hipFuncAttributeMaxDynamicSharedMemorySize, LDS_BYTES);

    char* ws = (char*)d_ws;
    const size_t MB = 1024 * 1024;
    _Float16* Xh    = (_Float16*)(ws + 0);        // 32 MiB
    _Float16* Wh    = (_Float16*)(ws + 32 * MB);  // 8 MiB [4][1024][1024]
    _Float16* qh    = (_Float16*)(ws + 40 * MB);  // 32 MiB
    _Float16* kh    = (_Float16*)(ws + 72 * MB);  // 32 MiB
    _Float16* vT    = (_Float16*)(ws + 104 * MB); // 32 MiB [1024][16384]
    _Float16* wt    = (_Float16*)(ws + 136 * MB); // 32 MiB
    _Float16* probs = (_Float16*)(ws + 168 * MB); // 64 MiB [8][2048][2048]
    float* scores   = (float*)(ws + 232 * MB);    // NB * 16 MiB scratch

    long nb_max = ((long)ws_size - 232 * (long)MB) / (16 * (long)MB);
    int NB = (int)(nb_max < 1 ? 1 : (nb_max > 8 ? 8 : nb_max));

    build_x_kernel<<<16384, 256, 0, stream>>>(e1, e2, e3, Xh);
    conv_w_kernel<<<4096, 256, 0, stream>>>(Wq, Wk, Wv, Wf, Wh);
    qkv_kernel<<<dim3(64, 4, 3), 512, LDS_BYTES, stream>>>(Xh, Wh, bq, bk, bv, qh, kh, vT);
    for (int b0 = 0; b0 < 8; b0 += NB) {
        int nb = 8 - b0 < NB ? 8 - b0 : NB;
        scores_kernel<<<dim3(8, 8, nb), 512, LDS_BYTES, stream>>>(qh, kh, scores, b0);
        softmax_kernel<<<dim3(2048, nb), 256, 0, stream>>>(scores, probs, b0);
    }
    pv_kernel<<<dim3(8, 4, 8), 512, LDS_BYTES, stream>>>(probs, vT, wt);
    out_kernel<<<dim3(64, 4), 512, LDS_BYTES, stream>>>(wt, Wh + 3 * 1048576, bf_, out);
}

// Round 4
// 528.566 us; speedup vs baseline: 1.0061x; 1.0061x over previous
//
#include <hip/hip_runtime.h>
#include <hip/hip_fp16.h>

typedef _Float16 half8 __attribute__((ext_vector_type(8)));
typedef _Float16 half4v __attribute__((ext_vector_type(4)));
typedef float floatx4 __attribute__((ext_vector_type(4)));

// ---------------- async global->LDS (16B per lane) ----------------
__device__ __forceinline__ void load_lds16(const void* g, void* l) {
    __builtin_amdgcn_global_load_lds(
        (const __attribute__((address_space(1))) void*)g,
        (__attribute__((address_space(3))) void*)l,
        16, 0, 0);
}

// Stage one 128x64 fp16 half-tile (16 KiB) into LDS. LDS dest is linear
// (global_load_lds requirement); the SOURCE slot is XOR-pre-swizzled
// (slot ^= row&7) so a swizzled reader sees natural data (Guideline 21).
__device__ __forceinline__ void stage_half(const _Float16* g, long ld, _Float16* dst) {
    const int t = threadIdx.x;  // 512 threads x 2 chunks x 16B
#pragma unroll
    for (int j = 0; j < 2; ++j) {
        const int c = j * 512 + t;             // 0..1023
        const int row = c >> 3;                // 0..127
        const int slot = (c & 7) ^ (row & 7);  // pre-swizzled source slot
        load_lds16(g + (long)row * ld + slot * 8, dst + c * 8);
    }
}

// ---------------- 256x256 8-phase gemm_bt core ----------------
// C[m,n] += sum_k A[m,k]*B[n,k]. BM=BN=256, BK=64, 512 threads = 8 waves
// (2M x 4N); per-wave 128x64 output = 8x4 frags of 16x16, mfma 16x16x32 f16.
// LDS: 2 tile-buffers x (A + B) x 2 halves x 16KB = 128 KiB (dynamic).
// Phases per K-tile decomposed by (m-half x n-half) QUADRANTS so ds_read
// work is spread 12/8/4/0 per phase (each burst hides under the previous
// phase's 16-MFMA drain) instead of 18/2/2/2 (serialized burst).
// Slot lifetimes (race-checked vs staging): A(buf) reads done by P2
// (STAGE_A into same buf at P3/P4 OK); B(buf) read P1+P3 (STAGE_B always
// targets other buf). vmcnt(4) at P4/P8 only; counted schedule unchanged.
__device__ __forceinline__ void gemm256_core(const _Float16* A, long lda,
                                             const _Float16* B, long ldb,
                                             int K, floatx4 acc[8][4],
                                             _Float16* lds) {
    const int lane = threadIdx.x & 63;
    const int w    = threadIdx.x >> 6;   // 0..7
    const int wr   = w >> 2;             // 0..1
    const int wc   = w & 3;              // 0..3
    const int rsel = lane & 15, gsel = lane >> 4;
    const int NT = K >> 6, NI = NT >> 1;

#define ASLOT(BUF, H) (lds + (BUF) * 32768 + (H) * 8192)
#define BSLOT(BUF, H) (lds + (BUF) * 32768 + 16384 + (H) * 8192)
#define STAGE_A(BUF, H, KT) stage_half(A + (long)(H) * 128 * lda + (KT) * 64, lda, ASLOT(BUF, H))
#define STAGE_B(BUF, H, KT) stage_half(B + (long)(H) * 128 * ldb + (KT) * 64, ldb, BSLOT(BUF, H))
// read 4 A m-frags (both k-halves) of m-half MH: 8 x ds_read_b128
#define READ_A(dst, BUF, MH)                                                       \
    {                                                                              \
        const _Float16* Ah = ASLOT(BUF, wr);                                       \
        _Pragma("unroll") for (int mi = 0; mi < 4; ++mi) {                         \
            const int r = ((MH) * 4 + mi) * 16 + rsel;                             \
            dst[mi][0] = *(const half8*)&Ah[r * 64 + ((gsel ^ (r & 7)) << 3)];     \
            dst[mi][1] = *(const half8*)&Ah[r * 64 + (((4 + gsel) ^ (r & 7)) << 3)]; \
        }                                                                          \
    }
// read 2 B n-frags (both k-halves) of n-half NH: 4 x ds_read_b128
#define READ_B(dst, BUF, NH)                                                       \
    {                                                                              \
        const _Float16* Bh = BSLOT(BUF, wc >> 1);                                  \
        _Pragma("unroll") for (int ni = 0; ni < 2; ++ni) {                         \
            const int rn = (wc & 1) * 64 + ((NH) * 2 + ni) * 16 + rsel;            \
            dst[ni][0] = *(const half8*)&Bh[rn * 64 + ((gsel ^ (rn & 7)) << 3)];   \
            dst[ni][1] = *(const half8*)&Bh[rn * 64 + (((4 + gsel) ^ (rn & 7)) << 3)]; \
        }                                                                          \
    }
// one quadrant: 4m x 2n x 2kh = 16 MFMA
#define BARRIER_MFMA(MH, NH, A_, B_)                                               \
    __builtin_amdgcn_sched_barrier(0);                                             \
    __builtin_amdgcn_s_barrier();                                                  \
    asm volatile("s_waitcnt lgkmcnt(0)" ::: "memory");                             \
    __builtin_amdgcn_sched_barrier(0);                                             \
    __builtin_amdgcn_s_setprio(1);                                                 \
    _Pragma("unroll") for (int mi = 0; mi < 4; ++mi)                               \
    _Pragma("unroll") for (int ni = 0; ni < 2; ++ni) {                             \
        acc[(MH) * 4 + mi][(NH) * 2 + ni] = __builtin_amdgcn_mfma_f32_16x16x32_f16( \
            A_[mi][0], B_[ni][0], acc[(MH) * 4 + mi][(NH) * 2 + ni], 0, 0, 0);     \
        acc[(MH) * 4 + mi][(NH) * 2 + ni] = __builtin_amdgcn_mfma_f32_16x16x32_f16( \
            A_[mi][1], B_[ni][1], acc[(MH) * 4 + mi][(NH) * 2 + ni], 0, 0, 0);     \
    }                                                                              \
    __builtin_amdgcn_s_setprio(0);                                                 \
    __builtin_amdgcn_s_barrier();                                                  \
    __builtin_amdgcn_sched_barrier(0);

    half8 a_lo[4][2], a_hi[4][2], b_lo[2][2], b_hi[2][2];

    // prologue: tile0 fully staged, tile1 A-halves in flight (4 loads)
    STAGE_A(0, 0, 0); STAGE_A(0, 1, 0); STAGE_B(0, 0, 0); STAGE_B(0, 1, 0);
    STAGE_A(1, 0, 1); STAGE_A(1, 1, 1);
    asm volatile("s_waitcnt vmcnt(4)" ::: "memory");
    __builtin_amdgcn_s_barrier();
    __builtin_amdgcn_sched_barrier(0);

#pragma unroll 1
    for (int i = 0; i < NI; ++i) {
        const int t1 = 2 * i + 1;
        const int s2 = (2 * i + 2 < NT) ? 2 * i + 2 : NT - 1;  // tail clamp:
        const int s3 = (2 * i + 3 < NT) ? 2 * i + 3 : NT - 1;  // never consumed
        // ---- tile 2i (buf0): quadrant phases, reads 12/8/4/0 ----
        READ_A(a_lo, 0, 0); READ_B(b_lo, 0, 0); STAGE_B(1, 0, t1);
        asm volatile("s_waitcnt lgkmcnt(8)" ::: "memory");  // partial pre-drain
        BARRIER_MFMA(0, 0, a_lo, b_lo);
        READ_A(a_hi, 0, 1); STAGE_B(1, 1, t1);
        BARRIER_MFMA(1, 0, a_hi, b_lo);
        READ_B(b_hi, 0, 1); STAGE_A(0, 0, s2);
        BARRIER_MFMA(0, 1, a_lo, b_hi);
        STAGE_A(0, 1, s2);
        asm volatile("s_waitcnt vmcnt(4)" ::: "memory");  // tile 2i+1 landed
        BARRIER_MFMA(1, 1, a_hi, b_hi);
        // ---- tile 2i+1 (buf1) ----
        READ_A(a_lo, 1, 0); READ_B(b_lo, 1, 0); STAGE_B(0, 0, s2);
        asm volatile("s_waitcnt lgkmcnt(8)" ::: "memory");
        BARRIER_MFMA(0, 0, a_lo, b_lo);
        READ_A(a_hi, 1, 1); STAGE_B(0, 1, s2);
        BARRIER_MFMA(1, 0, a_hi, b_lo);
        READ_B(b_hi, 1, 1); STAGE_A(1, 0, s3);
        BARRIER_MFMA(0, 1, a_lo, b_hi);
        STAGE_A(1, 1, s3);
        asm volatile("s_waitcnt vmcnt(4)" ::: "memory");  // tile 2i+2 landed
        BARRIER_MFMA(1, 1, a_hi, b_hi);
    }
    asm volatile("s_waitcnt vmcnt(0)" ::: "memory");
#undef ASLOT
#undef BSLOT
#undef STAGE_A
#undef STAGE_B
#undef READ_A
#undef READ_B
#undef BARRIER_MFMA
}

__device__ __forceinline__ void zero_acc8(floatx4 acc[8][4]) {
    const floatx4 z = {0.f, 0.f, 0.f, 0.f};
#pragma unroll
    for (int m = 0; m < 8; ++m)
#pragma unroll
        for (int n = 0; n < 4; ++n) acc[m][n] = z;
}

// ---------------- kernels ----------------

// concat embeddings [B,S,256|256|512] fp32 -> X fp16 [16384][1024]
__global__ __launch_bounds__(256) void build_x_kernel(const float* e1, const float* e2,
                                                      const float* e3, _Float16* X) {
    long i = ((long)blockIdx.x * 256 + threadIdx.x) * 4;
    int m = (int)(i >> 10);
    int c = (int)(i & 1023);
    const float* src;
    if (c < 256)      src = e1 + (long)m * 256 + c;
    else if (c < 512) src = e2 + (long)m * 256 + (c - 256);
    else              src = e3 + (long)m * 512 + (c - 512);
    float4 f = *(const float4*)src;
    half4v h;
    h[0] = (_Float16)f.x; h[1] = (_Float16)f.y;
    h[2] = (_Float16)f.z; h[3] = (_Float16)f.w;
    *(half4v*)&X[i] = h;
}

// Wq,Wk,Wv,Wf fp32 [1024][1024] -> Wh fp16 [4][1024][1024]
__global__ __launch_bounds__(256) void conv_w_kernel(const float* Wq, const float* Wk,
                                                     const float* Wv, const float* Wf,
                                                     _Float16* dst) {
    long i = ((long)blockIdx.x * 256 + threadIdx.x) * 4;
    int which = (int)(i >> 20);
    long off = i & 1048575;
    const float* w = which == 0 ? Wq : which == 1 ? Wk : which == 2 ? Wv : Wf;
    float4 f = *(const float4*)(w + off);
    half4v h;
    h[0] = (_Float16)f.x; h[1] = (_Float16)f.y;
    h[2] = (_Float16)f.z; h[3] = (_Float16)f.w;
    *(half4v*)&dst[i] = h;
}

// QKV projection: z=0 -> q, z=1 -> k (row-major [16384][1024]),
// z=2 -> v written TRANSPOSED as vT [1024][16384].
__global__ __launch_bounds__(512, 2) void qkv_kernel(const _Float16* X, const _Float16* W,
                                                     const float* bq, const float* bk,
                                                     const float* bv, _Float16* q,
                                                     _Float16* k, _Float16* vT) {
    extern __shared__ _Float16 lds[];
    const int m0 = blockIdx.x * 256;
    const int n0 = blockIdx.y * 256;
    const int z  = blockIdx.z;
    floatx4 acc[8][4];
    zero_acc8(acc);
    gemm256_core(X + (long)m0 * 1024, 1024,
                 W + (long)z * 1048576 + (long)n0 * 1024, 1024, 1024, acc, lds);

    const float* bias = (z == 0) ? bq : (z == 1) ? bk : bv;
    const int lane = threadIdx.x & 63;
    const int w = threadIdx.x >> 6;
    const int wr = w >> 2, wc = w & 3;
    const int r0 = m0 + wr * 128 + (lane >> 4) * 4;
    const int c0 = n0 + wc * 64 + (lane & 15);
#pragma unroll
    for (int m = 0; m < 8; ++m) {
#pragma unroll
        for (int n = 0; n < 4; ++n) {
            const int r = r0 + m * 16;
            const int c = c0 + n * 16;
            const float bb = bias[c];
            if (z == 2) {
                half4v vv;
#pragma unroll
                for (int j = 0; j < 4; ++j) vv[j] = (_Float16)(acc[m][n][j] + bb);
                *(half4v*)&vT[(long)c * 16384 + r] = vv;
            } else {
                _Float16* dst = (z == 0) ? q : k;
#pragma unroll
                for (int j = 0; j < 4; ++j)
                    dst[(long)(r + j) * 1024 + c] = (_Float16)(acc[m][n][j] + bb);
            }
        }
    }
}

// scores[b] = q[b] @ k[b]^T  (fp32 out, chunk-local batch index bz)
__global__ __launch_bounds__(512, 2) void scores_kernel(const _Float16* qh,
                                                        const _Float16* kh, float* scores,
                                                        int b0) {
    extern __shared__ _Float16 lds[];
    const int m0 = blockIdx.x * 256;
    const int n0 = blockIdx.y * 256;
    const int bz = blockIdx.z;
    const int batch = b0 + bz;
    float* C = scores + (long)bz * 2048 * 2048;
    floatx4 acc[8][4];
    zero_acc8(acc);
    gemm256_core(qh + ((long)batch * 2048 + m0) * 1024, 1024,
                 kh + ((long)batch * 2048 + n0) * 1024, 1024, 1024, acc, lds);

    const int lane = threadIdx.x & 63;
    const int w = threadIdx.x >> 6;
    const int wr = w >> 2, wc = w & 3;
    const int r0 = m0 + wr * 128 + (lane >> 4) * 4;
    const int c0 = n0 + wc * 64 + (lane & 15);
#pragma unroll
    for (int m = 0; m < 8; ++m) {
#pragma unroll
        for (int n = 0; n < 4; ++n) {
            const int r = r0 + m * 16;
            const int c = c0 + n * 16;
#pragma unroll
            for (int j = 0; j < 4; ++j)
                C[(long)(r + j) * 2048 + c] = acc[m][n][j];
        }
    }
}

// row softmax over 2048 fp32 scores -> fp16 probs. one block per row.
__global__ __launch_bounds__(256) void softmax_kernel(const float* scores,
                                                      _Float16* probs, int b0) {
    const int row = blockIdx.x;
    const int bz  = blockIdx.y;
    const float* s = scores + ((long)bz * 2048 + row) * 2048;
    _Float16* p = probs + ((long)(b0 + bz) * 2048 + row) * 2048;
    const int t = threadIdx.x;

    float4 x0 = ((const float4*)s)[t * 2];
    float4 x1 = ((const float4*)s)[t * 2 + 1];
    float v[8] = {x0.x, x0.y, x0.z, x0.w, x1.x, x1.y, x1.z, x1.w};

    float mx = v[0];
#pragma unroll
    for (int j = 1; j < 8; ++j) mx = fmaxf(mx, v[j]);
#pragma unroll
    for (int d = 1; d < 64; d <<= 1) mx = fmaxf(mx, __shfl_xor(mx, d));
    __shared__ float smax[4];
    __shared__ float ssum[4];
    if ((t & 63) == 0) smax[t >> 6] = mx;
    __syncthreads();
    mx = fmaxf(fmaxf(smax[0], smax[1]), fmaxf(smax[2], smax[3]));

    float e[8];
    float sum = 0.f;
#pragma unroll
    for (int j = 0; j < 8; ++j) {
        e[j] = __expf(v[j] - mx);
        sum += e[j];
    }
#pragma unroll
    for (int d = 1; d < 64; d <<= 1) sum += __shfl_xor(sum, d);
    if ((t & 63) == 0) ssum[t >> 6] = sum;
    __syncthreads();
    sum = ssum[0] + ssum[1] + ssum[2] + ssum[3];
    const float inv = 1.0f / sum;

    half8 o;
#pragma unroll
    for (int j = 0; j < 8; ++j) o[j] = (_Float16)(e[j] * inv);
    *(half8*)&p[t * 8] = o;
}

// weighted[b] = probs[b] @ v[b] via vT (gemm_bt form). fp16 out [16384][1024].
__global__ __launch_bounds__(512, 2) void pv_kernel(const _Float16* probs,
                                                    const _Float16* vT, _Float16* wt) {
    extern __shared__ _Float16 lds[];
    const int m0 = blockIdx.x * 256;
    const int n0 = blockIdx.y * 256;
    const int batch = blockIdx.z;
    floatx4 acc[8][4];
    zero_acc8(acc);
    gemm256_core(probs + ((long)batch * 2048 + m0) * 2048, 2048,
                 vT + (long)n0 * 16384 + (long)batch * 2048, 16384, 2048, acc, lds);

    const int lane = threadIdx.x & 63;
    const int w = threadIdx.x >> 6;
    const int wr = w >> 2, wc = w & 3;
    const int r0 = wr * 128 + (lane >> 4) * 4;
    const int c0 = n0 + wc * 64 + (lane & 15);
#pragma unroll
    for (int m = 0; m < 8; ++m) {
#pragma unroll
        for (int n = 0; n < 4; ++n) {
            const int r = r0 + m * 16;
            const int c = c0 + n * 16;
#pragma unroll
            for (int j = 0; j < 4; ++j)
                wt[((long)batch * 2048 + m0 + r + j) * 1024 + c] =
                    (_Float16)acc[m][n][j];
        }
    }
}

// out = leakyrelu(weighted @ Wf^T + bf), fp32 out.
__global__ __launch_bounds__(512, 2) void out_kernel(const _Float16* wt, const _Float16* Wf,
                                                     const float* bf_, float* out) {
    extern __shared__ _Float16 lds[];
    const int m0 = blockIdx.x * 256;
    const int n0 = blockIdx.y * 256;
    floatx4 acc[8][4];
    zero_acc8(acc);
    gemm256_core(wt + (long)m0 * 1024, 1024, Wf + (long)n0 * 1024, 1024, 1024, acc, lds);

    const int lane = threadIdx.x & 63;
    const int w = threadIdx.x >> 6;
    const int wr = w >> 2, wc = w & 3;
    const int r0 = m0 + wr * 128 + (lane >> 4) * 4;
    const int c0 = n0 + wc * 64 + (lane & 15);
#pragma unroll
    for (int m = 0; m < 8; ++m) {
#pragma unroll
        for (int n = 0; n < 4; ++n) {
            const int r = r0 + m * 16;
            const int c = c0 + n * 16;
            const float bb = bf_[c];
#pragma unroll
            for (int j = 0; j < 4; ++j) {
                float y = acc[m][n][j] + bb;
                y = (y >= 0.f) ? y : 0.2f * y;
                out[(long)(r + j) * 1024 + c] = y;
            }
        }
    }
}

// ---------------- launcher ----------------
extern "C" void kernel_launch(void* const* d_in, const int* in_sizes, int n_in,
                              void* d_out, int out_size, void* d_ws, size_t ws_size,
                              hipStream_t stream) {
    const float* e1 = (const float*)d_in[0];
    const float* e2 = (const float*)d_in[1];
    const float* e3 = (const float*)d_in[2];
    const float* Wq = (const float*)d_in[3];
    const float* bq = (const float*)d_in[4];
    const float* Wk = (const float*)d_in[5];
    const float* bk = (const float*)d_in[6];
    const float* Wv = (const float*)d_in[7];
    const float* bv = (const float*)d_in[8];
    const float* Wf = (const float*)d_in[9];
    const float* bf_ = (const float*)d_in[10];
    float* out = (float*)d_out;

    // raise dynamic-LDS cap to 128 KiB (idempotent; not a stream op)
    const int LDS_BYTES = 131072;
    (void)hipFuncSetAttribute((const void*)qkv_kernel,
                              hipFuncAttributeMaxDynamicSharedMemorySize, LDS_BYTES);
    (void)hipFuncSetAttribute((const void*)scores_kernel,
                              hipFuncAttributeMaxDynamicSharedMemorySize, LDS_BYTES);
    (void)hipFuncSetAttribute((const void*)pv_kernel,
                              hipFuncAttributeMaxDynamicSharedMemorySize, LDS_BYTES);
    (void)hipFuncSetAttribute((const void*)out_kernel,
                              hipFuncAttributeMaxDynamicSharedMemorySize, LDS_BYTES);

    char* ws = (char*)d_ws;
    const size_t MB = 1024 * 1024;
    _Float16* Xh    = (_Float16*)(ws + 0);        // 32 MiB
    _Float16* Wh    = (_Float16*)(ws + 32 * MB);  // 8 MiB [4][1024][1024]
    _Float16* qh    = (_Float16*)(ws + 40 * MB);  // 32 MiB
    _Float16* kh    = (_Float16*)(ws + 72 * MB);  // 32 MiB
    _Float16* vT    = (_Float16*)(ws + 104 * MB); // 32 MiB [1024][16384]
    _Float16* wt    = (_Float16*)(ws + 136 * MB); // 32 MiB
    _Float16* probs = (_Float16*)(ws + 168 * MB); // 64 MiB [8][2048][2048]
    float* scores   = (float*)(ws + 232 * MB);    // NB * 16 MiB scratch

    long nb_max = ((long)ws_size - 232 * (long)MB) / (16 * (long)MB);
    int NB = (int)(nb_max < 1 ? 1 : (nb_max > 8 ? 8 : nb_max));

    build_x_kernel<<<16384, 256, 0, stream>>>(e1, e2, e3, Xh);
    conv_w_kernel<<<4096, 256, 0, stream>>>(Wq, Wk, Wv, Wf, Wh);
    qkv_kernel<<<dim3(64, 4, 3), 512, LDS_BYTES, stream>>>(Xh, Wh, bq, bk, bv, qh, kh, vT);
    for (int b0 = 0; b0 < 8; b0 += NB) {
        int nb = 8 - b0 < NB ? 8 - b0 : NB;
        scores_kernel<<<dim3(8, 8, nb), 512, LDS_BYTES, stream>>>(qh, kh, scores, b0);
        softmax_kernel<<<dim3(2048, nb), 256, 0, stream>>>(scores, probs, b0);
    }
    pv_kernel<<<dim3(8, 4, 8), 512, LDS_BYTES, stream>>>(probs, vT, wt);
    out_kernel<<<dim3(64, 4), 512, LDS_BYTES, stream>>>(wt, Wh + 3 * 1048576, bf_, out);
}

// Round 5
// 486.291 us; speedup vs baseline: 1.0935x; 1.0869x over previous
//
#include <hip/hip_runtime.h>
#include <hip/hip_fp16.h>

typedef _Float16 half8 __attribute__((ext_vector_type(8)));
typedef _Float16 half4v __attribute__((ext_vector_type(4)));
typedef float floatx4 __attribute__((ext_vector_type(4)));

// ---------------- async global->LDS (16B per lane) ----------------
__device__ __forceinline__ void load_lds16(const void* g, void* l) {
    __builtin_amdgcn_global_load_lds(
        (const __attribute__((address_space(1))) void*)g,
        (__attribute__((address_space(3))) void*)l,
        16, 0, 0);
}

// Stage one 128x64 fp16 half-tile (16 KiB) into LDS. LDS dest is linear
// (global_load_lds requirement); the SOURCE slot is XOR-pre-swizzled
// (slot ^= row&7) so a swizzled reader sees natural data (Guideline 21).
__device__ __forceinline__ void stage_half(const _Float16* g, long ld, _Float16* dst) {
    const int t = threadIdx.x;  // 512 threads x 2 chunks x 16B
#pragma unroll
    for (int j = 0; j < 2; ++j) {
        const int c = j * 512 + t;             // 0..1023
        const int row = c >> 3;                // 0..127
        const int slot = (c & 7) ^ (row & 7);  // pre-swizzled source slot
        load_lds16(g + (long)row * ld + slot * 8, dst + c * 8);
    }
}

// ---------------- 256x256 gemm_bt core, ONE barrier per K-tile ----------------
// C[m,n] += sum_k A[m,k]*B[n,k]. BM=BN=256, BK=64, 512 threads = 8 waves
// (2M x 4N); per-wave 128x64 = 8x4 frags of 16x16, mfma 16x16x32 f16.
// LDS: 2 tile-buffers x (A 32K + B 32K)/... = 128 KiB.
// Loop invariant at tile t entry barrier: buf[t&1] staged & drained,
// all waves done reading buf[(t-1)&1]. Body: issue STAGE(t+1 -> buf[(t+1)&1])
// (legal: its readers finished at the entry barrier of t), then 24 ds_reads +
// 64 MFMA with NO pins -- compiler interleaves with counted lgkmcnt.
// End: per-wave vmcnt(0) (stage issued a full tile ago -> nearly free).
__device__ __forceinline__ void gemm256_core(const _Float16* A, long lda,
                                             const _Float16* B, long ldb,
                                             int K, floatx4 acc[8][4],
                                             _Float16* lds) {
    const int lane = threadIdx.x & 63;
    const int w    = threadIdx.x >> 6;   // 0..7
    const int wr   = w >> 2;             // 0..1
    const int wc   = w & 3;              // 0..3
    const int rsel = lane & 15, gsel = lane >> 4;
    const int NT = K >> 6;

#define STAGE(BUF, KT)                                                             \
    stage_half(A + (KT) * 64, lda, lds + (BUF) * 32768);                           \
    stage_half(A + (long)128 * lda + (KT) * 64, lda, lds + (BUF) * 32768 + 8192);  \
    stage_half(B + (KT) * 64, ldb, lds + (BUF) * 32768 + 16384);                   \
    stage_half(B + (long)128 * ldb + (KT) * 64, ldb, lds + (BUF) * 32768 + 24576);
#define READ_A(dst, AH, MH)                                                        \
    _Pragma("unroll") for (int mi = 0; mi < 4; ++mi) {                             \
        const int r = ((MH) * 4 + mi) * 16 + rsel;                                 \
        dst[mi][0] = *(const half8*)&(AH)[r * 64 + ((gsel ^ (r & 7)) << 3)];       \
        dst[mi][1] = *(const half8*)&(AH)[r * 64 + (((4 + gsel) ^ (r & 7)) << 3)]; \
    }
#define READ_B(dst, BH, NH)                                                        \
    _Pragma("unroll") for (int ni = 0; ni < 2; ++ni) {                             \
        const int rn = (wc & 1) * 64 + ((NH) * 2 + ni) * 16 + rsel;                \
        dst[ni][0] = *(const half8*)&(BH)[rn * 64 + ((gsel ^ (rn & 7)) << 3)];     \
        dst[ni][1] = *(const half8*)&(BH)[rn * 64 + (((4 + gsel) ^ (rn & 7)) << 3)]; \
    }
#define MFMA_Q(MH, NH, A_, B_)                                                     \
    _Pragma("unroll") for (int mi = 0; mi < 4; ++mi)                               \
    _Pragma("unroll") for (int ni = 0; ni < 2; ++ni) {                             \
        acc[(MH) * 4 + mi][(NH) * 2 + ni] = __builtin_amdgcn_mfma_f32_16x16x32_f16( \
            A_[mi][0], B_[ni][0], acc[(MH) * 4 + mi][(NH) * 2 + ni], 0, 0, 0);     \
        acc[(MH) * 4 + mi][(NH) * 2 + ni] = __builtin_amdgcn_mfma_f32_16x16x32_f16( \
            A_[mi][1], B_[ni][1], acc[(MH) * 4 + mi][(NH) * 2 + ni], 0, 0, 0);     \
    }

    half8 a_lo[4][2], a_hi[4][2], b_lo[2][2], b_hi[2][2];

    // prologue: stage tile 0, drain, rendezvous
    STAGE(0, 0);
    asm volatile("s_waitcnt vmcnt(0)" ::: "memory");
    __builtin_amdgcn_s_barrier();
    __builtin_amdgcn_sched_barrier(0);

#pragma unroll 1
    for (int t = 0; t < NT; ++t) {
        const int buf = t & 1;
        if (t + 1 < NT) { STAGE(buf ^ 1, t + 1); }
        const _Float16* Ah = lds + buf * 32768 + wr * 8192;
        const _Float16* Bh = lds + buf * 32768 + 16384 + (wc >> 1) * 8192;
        READ_A(a_lo, Ah, 0);
        READ_B(b_lo, Bh, 0);
        READ_A(a_hi, Ah, 1);
        READ_B(b_hi, Bh, 1);
        MFMA_Q(0, 0, a_lo, b_lo);
        MFMA_Q(1, 0, a_hi, b_lo);
        MFMA_Q(0, 1, a_lo, b_hi);
        MFMA_Q(1, 1, a_hi, b_hi);
        // own stage loads (issued a full tile ago) must land before rendezvous
        asm volatile("s_waitcnt vmcnt(0)" ::: "memory");
        __builtin_amdgcn_s_barrier();
        __builtin_amdgcn_sched_barrier(0);
    }
#undef STAGE
#undef READ_A
#undef READ_B
#undef MFMA_Q
}

__device__ __forceinline__ void zero_acc8(floatx4 acc[8][4]) {
    const floatx4 z = {0.f, 0.f, 0.f, 0.f};
#pragma unroll
    for (int m = 0; m < 8; ++m)
#pragma unroll
        for (int n = 0; n < 4; ++n) acc[m][n] = z;
}

// ---------------- kernels ----------------

// concat embeddings [B,S,256|256|512] fp32 -> X fp16 [16384][1024]
__global__ __launch_bounds__(256) void build_x_kernel(const float* e1, const float* e2,
                                                      const float* e3, _Float16* X) {
    long i = ((long)blockIdx.x * 256 + threadIdx.x) * 4;
    int m = (int)(i >> 10);
    int c = (int)(i & 1023);
    const float* src;
    if (c < 256)      src = e1 + (long)m * 256 + c;
    else if (c < 512) src = e2 + (long)m * 256 + (c - 256);
    else              src = e3 + (long)m * 512 + (c - 512);
    float4 f = *(const float4*)src;
    half4v h;
    h[0] = (_Float16)f.x; h[1] = (_Float16)f.y;
    h[2] = (_Float16)f.z; h[3] = (_Float16)f.w;
    *(half4v*)&X[i] = h;
}

// Wq,Wk,Wv,Wf fp32 [1024][1024] -> Wh fp16 [4][1024][1024]
__global__ __launch_bounds__(256) void conv_w_kernel(const float* Wq, const float* Wk,
                                                     const float* Wv, const float* Wf,
                                                     _Float16* dst) {
    long i = ((long)blockIdx.x * 256 + threadIdx.x) * 4;
    int which = (int)(i >> 20);
    long off = i & 1048575;
    const float* w = which == 0 ? Wq : which == 1 ? Wk : which == 2 ? Wv : Wf;
    float4 f = *(const float4*)(w + off);
    half4v h;
    h[0] = (_Float16)f.x; h[1] = (_Float16)f.y;
    h[2] = (_Float16)f.z; h[3] = (_Float16)f.w;
    *(half4v*)&dst[i] = h;
}

// QKV projection: z=0 -> q, z=1 -> k (row-major [16384][1024]),
// z=2 -> v written TRANSPOSED as vT [1024][16384] via LDS transpose
// (direct scatter was 8B/lane at 32KB stride -> write amplification).
__global__ __launch_bounds__(512, 2) void qkv_kernel(const _Float16* X, const _Float16* W,
                                                     const float* bq, const float* bk,
                                                     const float* bv, _Float16* q,
                                                     _Float16* k, _Float16* vT) {
    extern __shared__ _Float16 lds[];
    const int m0 = blockIdx.x * 256;
    const int n0 = blockIdx.y * 256;
    const int z  = blockIdx.z;
    floatx4 acc[8][4];
    zero_acc8(acc);
    gemm256_core(X + (long)m0 * 1024, 1024,
                 W + (long)z * 1048576 + (long)n0 * 1024, 1024, 1024, acc, lds);

    const float* bias = (z == 0) ? bq : (z == 1) ? bk : bv;
    const int lane = threadIdx.x & 63;
    const int w = threadIdx.x >> 6;
    const int wr = w >> 2, wc = w & 3;
    const int rsel = lane & 15, gsel = lane >> 4;

    if (z == 2) {
        // ---- bias + fp16 cvt into LDS [c][r], XOR-swizzled r to spread banks
        const int rb = wr * 128 + gsel * 4;   // + mI*16 (+j)
        const int cb = wc * 64 + rsel;        // + nI*16
#pragma unroll
        for (int mI = 0; mI < 8; ++mI) {
#pragma unroll
            for (int nI = 0; nI < 4; ++nI) {
                const int c = cb + nI * 16;
                const int r = rb + mI * 16;
                const float bb = bias[n0 + c];
                half4v vv;
#pragma unroll
                for (int j = 0; j < 4; ++j) vv[j] = (_Float16)(acc[mI][nI][j] + bb);
                *(half4v*)&lds[c * 256 + (r ^ ((c & 7) << 3))] = vv;
            }
        }
        __syncthreads();
        // ---- write vT rows: 256 cols x 32 chunks of 16B, contiguous in m
#pragma unroll
        for (int it = 0; it < 16; ++it) {
            const int idx = it * 512 + threadIdx.x;  // 0..8191
            const int c = idx >> 5;                  // 0..255
            const int mc = idx & 31;                 // 16B chunk
            half8 v = *(const half8*)&lds[c * 256 + ((mc * 8) ^ ((c & 7) << 3))];
            *(half8*)&vT[(long)(n0 + c) * 16384 + m0 + mc * 8] = v;
        }
    } else {
        _Float16* dst = (z == 0) ? q : k;
        const int r0 = m0 + wr * 128 + gsel * 4;
        const int c0 = n0 + wc * 64 + rsel;
#pragma unroll
        for (int mI = 0; mI < 8; ++mI) {
#pragma unroll
            for (int nI = 0; nI < 4; ++nI) {
                const int r = r0 + mI * 16;
                const int c = c0 + nI * 16;
                const float bb = bias[c];
#pragma unroll
                for (int j = 0; j < 4; ++j)
                    dst[(long)(r + j) * 1024 + c] = (_Float16)(acc[mI][nI][j] + bb);
            }
        }
    }
}

// scores[b] = q[b] @ k[b]^T  (fp32 out, chunk-local batch index bz)
__global__ __launch_bounds__(512, 2) void scores_kernel(const _Float16* qh,
                                                        const _Float16* kh, float* scores,
                                                        int b0) {
    extern __shared__ _Float16 lds[];
    const int m0 = blockIdx.x * 256;
    const int n0 = blockIdx.y * 256;
    const int bz = blockIdx.z;
    const int batch = b0 + bz;
    float* C = scores + (long)bz * 2048 * 2048;
    floatx4 acc[8][4];
    zero_acc8(acc);
    gemm256_core(qh + ((long)batch * 2048 + m0) * 1024, 1024,
                 kh + ((long)batch * 2048 + n0) * 1024, 1024, 1024, acc, lds);

    const int lane = threadIdx.x & 63;
    const int w = threadIdx.x >> 6;
    const int wr = w >> 2, wc = w & 3;
    const int r0 = m0 + wr * 128 + (lane >> 4) * 4;
    const int c0 = n0 + wc * 64 + (lane & 15);
#pragma unroll
    for (int m = 0; m < 8; ++m) {
#pragma unroll
        for (int n = 0; n < 4; ++n) {
            const int r = r0 + m * 16;
            const int c = c0 + n * 16;
#pragma unroll
            for (int j = 0; j < 4; ++j)
                C[(long)(r + j) * 2048 + c] = acc[m][n][j];
        }
    }
}

// row softmax over 2048 fp32 scores -> fp16 probs. one block per row.
__global__ __launch_bounds__(256) void softmax_kernel(const float* scores,
                                                      _Float16* probs, int b0) {
    const int row = blockIdx.x;
    const int bz  = blockIdx.y;
    const float* s = scores + ((long)bz * 2048 + row) * 2048;
    _Float16* p = probs + ((long)(b0 + bz) * 2048 + row) * 2048;
    const int t = threadIdx.x;

    float4 x0 = ((const float4*)s)[t * 2];
    float4 x1 = ((const float4*)s)[t * 2 + 1];
    float v[8] = {x0.x, x0.y, x0.z, x0.w, x1.x, x1.y, x1.z, x1.w};

    float mx = v[0];
#pragma unroll
    for (int j = 1; j < 8; ++j) mx = fmaxf(mx, v[j]);
#pragma unroll
    for (int d = 1; d < 64; d <<= 1) mx = fmaxf(mx, __shfl_xor(mx, d));
    __shared__ float smax[4];
    __shared__ float ssum[4];
    if ((t & 63) == 0) smax[t >> 6] = mx;
    __syncthreads();
    mx = fmaxf(fmaxf(smax[0], smax[1]), fmaxf(smax[2], smax[3]));

    float e[8];
    float sum = 0.f;
#pragma unroll
    for (int j = 0; j < 8; ++j) {
        e[j] = __expf(v[j] - mx);
        sum += e[j];
    }
#pragma unroll
    for (int d = 1; d < 64; d <<= 1) sum += __shfl_xor(sum, d);
    if ((t & 63) == 0) ssum[t >> 6] = sum;
    __syncthreads();
    sum = ssum[0] + ssum[1] + ssum[2] + ssum[3];
    const float inv = 1.0f / sum;

    half8 o;
#pragma unroll
    for (int j = 0; j < 8; ++j) o[j] = (_Float16)(e[j] * inv);
    *(half8*)&p[t * 8] = o;
}

// weighted[b] = probs[b] @ v[b] via vT (gemm_bt form). fp16 out [16384][1024].
__global__ __launch_bounds__(512, 2) void pv_kernel(const _Float16* probs,
                                                    const _Float16* vT, _Float16* wt) {
    extern __shared__ _Float16 lds[];
    const int m0 = blockIdx.x * 256;
    const int n0 = blockIdx.y * 256;
    const int batch = blockIdx.z;
    floatx4 acc[8][4];
    zero_acc8(acc);
    gemm256_core(probs + ((long)batch * 2048 + m0) * 2048, 2048,
                 vT + (long)n0 * 16384 + (long)batch * 2048, 16384, 2048, acc, lds);

    const int lane = threadIdx.x & 63;
    const int w = threadIdx.x >> 6;
    const int wr = w >> 2, wc = w & 3;
    const int r0 = wr * 128 + (lane >> 4) * 4;
    const int c0 = n0 + wc * 64 + (lane & 15);
#pragma unroll
    for (int m = 0; m < 8; ++m) {
#pragma unroll
        for (int n = 0; n < 4; ++n) {
            const int r = r0 + m * 16;
            const int c = c0 + n * 16;
#pragma unroll
            for (int j = 0; j < 4; ++j)
                wt[((long)batch * 2048 + m0 + r + j) * 1024 + c] =
                    (_Float16)acc[m][n][j];
        }
    }
}

// out = leakyrelu(weighted @ Wf^T + bf), fp32 out.
__global__ __launch_bounds__(512, 2) void out_kernel(const _Float16* wt, const _Float16* Wf,
                                                     const float* bf_, float* out) {
    extern __shared__ _Float16 lds[];
    const int m0 = blockIdx.x * 256;
    const int n0 = blockIdx.y * 256;
    floatx4 acc[8][4];
    zero_acc8(acc);
    gemm256_core(wt + (long)m0 * 1024, 1024, Wf + (long)n0 * 1024, 1024, 1024, acc, lds);

    const int lane = threadIdx.x & 63;
    const int w = threadIdx.x >> 6;
    const int wr = w >> 2, wc = w & 3;
    const int r0 = m0 + wr * 128 + (lane >> 4) * 4;
    const int c0 = n0 + wc * 64 + (lane & 15);
#pragma unroll
    for (int m = 0; m < 8; ++m) {
#pragma unroll
        for (int n = 0; n < 4; ++n) {
            const int r = r0 + m * 16;
            const int c = c0 + n * 16;
            const float bb = bf_[c];
#pragma unroll
            for (int j = 0; j < 4; ++j) {
                float y = acc[m][n][j] + bb;
                y = (y >= 0.f) ? y : 0.2f * y;
                out[(long)(r + j) * 1024 + c] = y;
            }
        }
    }
}

// ---------------- launcher ----------------
extern "C" void kernel_launch(void* const* d_in, const int* in_sizes, int n_in,
                              void* d_out, int out_size, void* d_ws, size_t ws_size,
                              hipStream_t stream) {
    const float* e1 = (const float*)d_in[0];
    const float* e2 = (const float*)d_in[1];
    const float* e3 = (const float*)d_in[2];
    const float* Wq = (const float*)d_in[3];
    const float* bq = (const float*)d_in[4];
    const float* Wk = (const float*)d_in[5];
    const float* bk = (const float*)d_in[6];
    const float* Wv = (const float*)d_in[7];
    const float* bv = (const float*)d_in[8];
    const float* Wf = (const float*)d_in[9];
    const float* bf_ = (const float*)d_in[10];
    float* out = (float*)d_out;

    // raise dynamic-LDS cap to 128 KiB (idempotent; not a stream op)
    const int LDS_BYTES = 131072;
    (void)hipFuncSetAttribute((const void*)qkv_kernel,
                              hipFuncAttributeMaxDynamicSharedMemorySize, LDS_BYTES);
    (void)hipFuncSetAttribute((const void*)scores_kernel,
                              hipFuncAttributeMaxDynamicSharedMemorySize, LDS_BYTES);
    (void)hipFuncSetAttribute((const void*)pv_kernel,
                              hipFuncAttributeMaxDynamicSharedMemorySize, LDS_BYTES);
    (void)hipFuncSetAttribute((const void*)out_kernel,
                              hipFuncAttributeMaxDynamicSharedMemorySize, LDS_BYTES);

    char* ws = (char*)d_ws;
    const size_t MB = 1024 * 1024;
    _Float16* Xh    = (_Float16*)(ws + 0);        // 32 MiB
    _Float16* Wh    = (_Float16*)(ws + 32 * MB);  // 8 MiB [4][1024][1024]
    _Float16* qh    = (_Float16*)(ws + 40 * MB);  // 32 MiB
    _Float16* kh    = (_Float16*)(ws + 72 * MB);  // 32 MiB
    _Float16* vT    = (_Float16*)(ws + 104 * MB); // 32 MiB [1024][16384]
    _Float16* wt    = (_Float16*)(ws + 136 * MB); // 32 MiB
    _Float16* probs = (_Float16*)(ws + 168 * MB); // 64 MiB [8][2048][2048]
    float* scores   = (float*)(ws + 232 * MB);    // NB * 16 MiB scratch

    long nb_max = ((long)ws_size - 232 * (long)MB) / (16 * (long)MB);
    int NB = (int)(nb_max < 1 ? 1 : (nb_max > 8 ? 8 : nb_max));

    build_x_kernel<<<16384, 256, 0, stream>>>(e1, e2, e3, Xh);
    conv_w_kernel<<<4096, 256, 0, stream>>>(Wq, Wk, Wv, Wf, Wh);
    qkv_kernel<<<dim3(64, 4, 3), 512, LDS_BYTES, stream>>>(Xh, Wh, bq, bk, bv, qh, kh, vT);
    for (int b0 = 0; b0 < 8; b0 += NB) {
        int nb = 8 - b0 < NB ? 8 - b0 : NB;
        scores_kernel<<<dim3(8, 8, nb), 512, LDS_BYTES, stream>>>(qh, kh, scores, b0);
        softmax_kernel<<<dim3(2048, nb), 256, 0, stream>>>(scores, probs, b0);
    }
    pv_kernel<<<dim3(8, 4, 8), 512, LDS_BYTES, stream>>>(probs, vT, wt);
    out_kernel<<<dim3(64, 4), 512, LDS_BYTES, stream>>>(wt, Wh + 3 * 1048576, bf_, out);
}